// Round 1
// baseline (2233.854 us; speedup 1.0000x reference)
//
#include <hip/hip_runtime.h>
#include <math.h>

#define NN 20000
#define EE 60000
#define BB 512
#define HC 1024
#define HH 4
#define CC 256

// ---------------- helpers ----------------
__device__ __forceinline__ void atomicMaxF(float* addr, float val) {
    int* ia = (int*)addr;
    int old = *ia;
    while (__int_as_float(old) < val) {
        int assumed = old;
        old = atomicCAS(ia, assumed, __float_as_int(val));
        if (old == assumed) break;
    }
}

// ---------------- precompute kernels ----------------
__global__ void ea_sum_kernel(const float* __restrict__ ea, float* sums, int E_) {
    float s0 = 0.f, s1 = 0.f, s2 = 0.f;
    for (int e = blockIdx.x * 256 + threadIdx.x; e < E_; e += gridDim.x * 256) {
        s0 += ea[e * 3 + 0];
        s1 += ea[e * 3 + 1];
        s2 += ea[e * 3 + 2];
    }
    for (int o = 32; o; o >>= 1) {
        s0 += __shfl_down(s0, o);
        s1 += __shfl_down(s1, o);
        s2 += __shfl_down(s2, o);
    }
    if ((threadIdx.x & 63) == 0) {
        atomicAdd(&sums[0], s0);
        atomicAdd(&sums[1], s1);
        atomicAdd(&sums[2], s2);
    }
}

__global__ void hist_kernel(const int* __restrict__ ei, int* counts, int E_) {
    int e = blockIdx.x * 256 + threadIdx.x;
    if (e < E_) atomicAdd(&counts[ei[E_ + e]], 1);
}

__global__ void scan_kernel(const int* __restrict__ counts, int* indptr, int n) {
    __shared__ int sdata[1024];
    int t = threadIdx.x;
    int carry = 0;
    if (t == 0) indptr[0] = 0;
    for (int base = 0; base < n; base += 1024) {
        int i = base + t;
        int v = (i < n) ? counts[i] : 0;
        sdata[t] = v;
        __syncthreads();
        for (int off = 1; off < 1024; off <<= 1) {
            int tmp = (t >= off) ? sdata[t - off] : 0;
            __syncthreads();
            sdata[t] += tmp;
            __syncthreads();
        }
        if (i < n) indptr[i + 1] = carry + sdata[t];
        int total = sdata[1023];
        __syncthreads();
        carry += total;
    }
}

__global__ void scatter_kernel(const int* __restrict__ ei, const int* __restrict__ indptr,
                               int* fill, int* sorted, int E_) {
    int e = blockIdx.x * 256 + threadIdx.x;
    if (e >= E_) return;
    int d = ei[E_ + e];
    int pos = indptr[d] + atomicAdd(&fill[d], 1);
    sorted[pos] = e;
}

__global__ void bptr_kernel(const int* __restrict__ batch, int* bptr, int n, int nb) {
    int i = blockIdx.x * 256 + threadIdx.x;
    if (i >= n) return;
    int b = batch[i];
    if (i == 0) {
        for (int bb = 0; bb <= b; bb++) bptr[bb] = 0;
    } else {
        int pb = batch[i - 1];
        if (pb != b) {
            for (int bb = pb + 1; bb <= b; bb++) bptr[bb] = i;
        }
    }
    if (i == n - 1) {
        for (int bb = b + 1; bb <= nb; bb++) bptr[bb] = n;
    }
}

// ---------------- GEMMs ----------------
// layer 0: h = x @ w0, K=7
__global__ void gemm7_kernel(const float* __restrict__ x, const float* __restrict__ w0,
                             float* __restrict__ h) {
    int n = blockIdx.x;
    int j = blockIdx.y * 256 + threadIdx.x;
    float acc = 0.f;
#pragma unroll
    for (int f = 0; f < 7; f++) acc += x[n * 7 + f] * w0[f * HC + j];
    h[(size_t)n * HC + j] = acc;
}

// layers 1-3: C[M,Nc] = A[M,K] @ B[K,Nc], fp32, tile 128x128x16, 8x8 per thread
#define BM 128
#define BN 128
#define BK 16
__global__ __launch_bounds__(256) void sgemm_kernel(const float* __restrict__ A,
                                                    const float* __restrict__ Bm,
                                                    float* __restrict__ C,
                                                    int M, int Nc, int K) {
    __shared__ float As[BK][BM];
    __shared__ float Bs[BK][BN];
    int t = threadIdx.x;
    int tx = t & 15, ty = t >> 4;
    int m0 = blockIdx.y * BM;
    int n0 = blockIdx.x * BN;
    float acc[8][8];
#pragma unroll
    for (int i = 0; i < 8; i++)
#pragma unroll
        for (int j = 0; j < 8; j++) acc[i][j] = 0.f;

    for (int k0 = 0; k0 < K; k0 += BK) {
        __syncthreads();
#pragma unroll
        for (int i = 0; i < 2; i++) {
            int idx = t * 2 + i;          // 0..511
            int row = idx >> 2;
            int cf = idx & 3;
            int gr = m0 + row;
            float4 v = make_float4(0.f, 0.f, 0.f, 0.f);
            if (gr < M) v = *(const float4*)&A[(size_t)gr * K + k0 + cf * 4];
            As[cf * 4 + 0][row] = v.x;
            As[cf * 4 + 1][row] = v.y;
            As[cf * 4 + 2][row] = v.z;
            As[cf * 4 + 3][row] = v.w;
        }
#pragma unroll
        for (int i = 0; i < 2; i++) {
            int idx = t * 2 + i;
            int rk = idx >> 5;
            int cf = idx & 31;
            float4 v = *(const float4*)&Bm[(size_t)(k0 + rk) * Nc + n0 + cf * 4];
            *(float4*)&Bs[rk][cf * 4] = v;
        }
        __syncthreads();
#pragma unroll
        for (int kk = 0; kk < BK; kk++) {
            float a[8], b[8];
            *(float4*)&a[0] = *(const float4*)&As[kk][ty * 8];
            *(float4*)&a[4] = *(const float4*)&As[kk][ty * 8 + 4];
            *(float4*)&b[0] = *(const float4*)&Bs[kk][tx * 8];
            *(float4*)&b[4] = *(const float4*)&Bs[kk][tx * 8 + 4];
#pragma unroll
            for (int ii = 0; ii < 8; ii++)
#pragma unroll
                for (int jj = 0; jj < 8; jj++) acc[ii][jj] += a[ii] * b[jj];
        }
    }
#pragma unroll
    for (int ii = 0; ii < 8; ii++) {
        int r = m0 + ty * 8 + ii;
        if (r < M) {
            *(float4*)&C[(size_t)r * Nc + n0 + tx * 8] =
                make_float4(acc[ii][0], acc[ii][1], acc[ii][2], acc[ii][3]);
            *(float4*)&C[(size_t)r * Nc + n0 + tx * 8 + 4] =
                make_float4(acc[ii][4], acc[ii][5], acc[ii][6], acc[ii][7]);
        }
    }
}

// ---------------- attention kernels ----------------
// M[d,h] = sum_c We[layer,d,h*C+c]*a_e[layer,h,c]; ae_self[h] = sum_d mean_ea[d]*M[d,h]
__global__ void mmat_kernel(const float* __restrict__ w_edge, const float* __restrict__ att_edge,
                            const float* __restrict__ ea_sums, float* Mmat, float* ae_self,
                            int layer, float invE) {
    __shared__ float red[256];
    __shared__ float Ms[12];
    int t = threadIdx.x;
    for (int dh = 0; dh < 12; dh++) {
        int d = dh >> 2, hh = dh & 3;
        float v = w_edge[layer * 3072 + d * HC + hh * CC + t] *
                  att_edge[layer * HC + hh * CC + t];
        red[t] = v;
        __syncthreads();
        for (int o = 128; o; o >>= 1) {
            if (t < o) red[t] += red[t + o];
            __syncthreads();
        }
        if (t == 0) {
            Ms[dh] = red[0];
            Mmat[dh] = red[0];
        }
        __syncthreads();
    }
    if (t < 4) {
        float v = 0.f;
        for (int d = 0; d < 3; d++) v += ea_sums[d] * invE * Ms[d * 4 + t];
        ae_self[t] = v;
    }
}

// per node: asrc[n,h], adst[n,h]
__global__ void alpha_kernel(const float* __restrict__ h, const float* __restrict__ att_src,
                             const float* __restrict__ att_dst, float* asrc, float* adst,
                             int layer) {
    int n = blockIdx.x;
    int t = threadIdx.x;
    int w = t >> 6, lane = t & 63;
    const float4 hv = *(const float4*)&h[(size_t)n * HC + w * CC + lane * 4];
    const float4 s4 = *(const float4*)&att_src[layer * HC + w * CC + lane * 4];
    const float4 d4 = *(const float4*)&att_dst[layer * HC + w * CC + lane * 4];
    float ss = hv.x * s4.x + hv.y * s4.y + hv.z * s4.z + hv.w * s4.w;
    float sd = hv.x * d4.x + hv.y * d4.y + hv.z * d4.z + hv.w * d4.w;
    for (int o = 32; o; o >>= 1) {
        ss += __shfl_down(ss, o);
        sd += __shfl_down(sd, o);
    }
    if (lane == 0) {
        asrc[n * 4 + w] = ss;
        adst[n * 4 + w] = sd;
    }
}

// self-loop raw alpha + amax init
__global__ void self_kernel(const float* __restrict__ asrc, const float* __restrict__ adst,
                            const float* __restrict__ ae_self, float* self_raw, float* amax) {
    int n = blockIdx.x * 256 + threadIdx.x;
    if (n >= NN) return;
    float4 as4 = *(const float4*)&asrc[n * 4];
    float4 ad4 = *(const float4*)&adst[n * 4];
    float r[4];
    r[0] = as4.x + ad4.x + ae_self[0];
    r[1] = as4.y + ad4.y + ae_self[1];
    r[2] = as4.z + ad4.z + ae_self[2];
    r[3] = as4.w + ad4.w + ae_self[3];
#pragma unroll
    for (int k = 0; k < 4; k++) r[k] = (r[k] > 0.f) ? r[k] : 0.2f * r[k];
    *(float4*)&self_raw[n * 4] = make_float4(r[0], r[1], r[2], r[3]);
    *(float4*)&amax[n * 4] = make_float4(r[0], r[1], r[2], r[3]);
}

// per edge: raw alpha + atomic max into amax[dst]
__global__ void edge_raw_kernel(const int* __restrict__ ei, const float* __restrict__ ea,
                                const float* __restrict__ Mmat, const float* __restrict__ asrc,
                                const float* __restrict__ adst, float* raw, float* amax) {
    int e = blockIdx.x * 256 + threadIdx.x;
    if (e >= EE) return;
    int s = ei[e], d = ei[EE + e];
    float a0 = ea[e * 3 + 0], a1 = ea[e * 3 + 1], a2 = ea[e * 3 + 2];
    float4 as4 = *(const float4*)&asrc[s * 4];
    float4 ad4 = *(const float4*)&adst[d * 4];
    float asl[4] = {as4.x, as4.y, as4.z, as4.w};
    float adl[4] = {ad4.x, ad4.y, ad4.z, ad4.w};
#pragma unroll
    for (int h = 0; h < 4; h++) {
        float aeh = a0 * Mmat[h] + a1 * Mmat[4 + h] + a2 * Mmat[8 + h];
        float r = asl[h] + adl[h] + aeh;
        r = (r > 0.f) ? r : 0.2f * r;
        raw[e * 4 + h] = r;
        atomicMaxF(&amax[d * 4 + h], r);
    }
}

// p_self = exp(self_raw - amax); denom init
__global__ void self2_kernel(const float* __restrict__ self_raw, const float* __restrict__ amax,
                             float* p_self, float* denom) {
    int n = blockIdx.x * 256 + threadIdx.x;
    if (n >= NN) return;
    float4 sr = *(const float4*)&self_raw[n * 4];
    float4 am = *(const float4*)&amax[n * 4];
    float4 p;
    p.x = expf(sr.x - am.x);
    p.y = expf(sr.y - am.y);
    p.z = expf(sr.z - am.z);
    p.w = expf(sr.w - am.w);
    *(float4*)&p_self[n * 4] = p;
    *(float4*)&denom[n * 4] = p;
}

// per edge: p = exp(raw - amax[dst]); denom accumulate
__global__ void edge_p_kernel(const int* __restrict__ ei, float* raw_p,
                              const float* __restrict__ amax, float* denom) {
    int e = blockIdx.x * 256 + threadIdx.x;
    if (e >= EE) return;
    int d = ei[EE + e];
#pragma unroll
    for (int h = 0; h < 4; h++) {
        float p = expf(raw_p[e * 4 + h] - amax[d * 4 + h]);
        raw_p[e * 4 + h] = p;
        atomicAdd(&denom[d * 4 + h], p);
    }
}

// per node aggregation: out = (sum p*h[src] + p_self*h[n]) / denom, + bias (+BN+ReLU or head-mean)
__global__ void agg_kernel(const float* __restrict__ h_lin, const float* __restrict__ p_e,
                           const float* __restrict__ p_self, const float* __restrict__ denom,
                           const int* __restrict__ indptr, const int* __restrict__ sorted,
                           const int* __restrict__ ei, const float* __restrict__ bias012,
                           const float* __restrict__ bias3, const float* __restrict__ bn_g,
                           const float* __restrict__ bn_b, const float* __restrict__ bn_m,
                           const float* __restrict__ bn_v, float* __restrict__ out,
                           int layer, int concat) {
    __shared__ float buf[1024];
    int n = blockIdx.x, t = threadIdx.x;
    int h = t >> 6;
    int c4 = t * 4;
    float ax = 0.f, ay = 0.f, az = 0.f, aw = 0.f;
    int s = indptr[n], epos = indptr[n + 1];
    for (int idx = s; idx < epos; idx++) {
        int eid = sorted[idx];
        int sr = ei[eid];
        float pe = p_e[eid * 4 + h];
        const float4 v = *(const float4*)&h_lin[(size_t)sr * HC + c4];
        ax += pe * v.x; ay += pe * v.y; az += pe * v.z; aw += pe * v.w;
    }
    {
        float ps = p_self[n * 4 + h];
        const float4 v = *(const float4*)&h_lin[(size_t)n * HC + c4];
        ax += ps * v.x; ay += ps * v.y; az += ps * v.z; aw += ps * v.w;
    }
    float inv = 1.0f / (denom[n * 4 + h] + 1e-16f);
    ax *= inv; ay *= inv; az *= inv; aw *= inv;
    if (concat) {
        float vals[4] = {ax, ay, az, aw};
        float4 o;
        float* po = &o.x;
#pragma unroll
        for (int k = 0; k < 4; k++) {
            int j = c4 + k;
            float val = vals[k] + bias012[layer * HC + j];
            float g = bn_g[layer * HC + j];
            float be = bn_b[layer * HC + j];
            float mu = bn_m[layer * HC + j];
            float va = bn_v[layer * HC + j];
            val = (val - mu) * (g * rsqrtf(va + 1e-5f)) + be;
            po[k] = fmaxf(val, 0.f);
        }
        *(float4*)&out[(size_t)n * HC + c4] = o;
    } else {
        buf[c4 + 0] = ax;
        buf[c4 + 1] = ay;
        buf[c4 + 2] = az;
        buf[c4 + 3] = aw;
        __syncthreads();
        if (t < 64) {
#pragma unroll
            for (int k = 0; k < 4; k++) {
                int c = t * 4 + k;
                float v2 = 0.25f * (buf[c] + buf[256 + c] + buf[512 + c] + buf[768 + c]) +
                           bias3[c];
                out[(size_t)n * CC + c] = v2;
            }
        }
    }
}

// ---------------- readout ----------------
__global__ void gate_kernel(const float* __restrict__ h3, const float* __restrict__ gw,
                            const float* __restrict__ gb, float* gate) {
    int node = blockIdx.x * 4 + (threadIdx.x >> 6);
    int lane = threadIdx.x & 63;
    if (node >= NN) return;
    const float4 hv = *(const float4*)&h3[(size_t)node * CC + lane * 4];
    const float4 w4 = *(const float4*)&gw[lane * 4];
    float s = hv.x * w4.x + hv.y * w4.y + hv.z * w4.z + hv.w * w4.w;
    for (int o = 32; o; o >>= 1) s += __shfl_down(s, o);
    if (lane == 0) gate[node] = s + gb[0];
}

__global__ void graphagg_kernel(const float* __restrict__ gate, const float* __restrict__ h3,
                                const int* __restrict__ bptr, float* __restrict__ graph) {
    __shared__ float red[256];
    __shared__ float wn[256];
    int b = blockIdx.x, t = threadIdx.x;
    int s = bptr[b], epos = bptr[b + 1];
    float m = -3.4e38f;
    for (int n = s + t; n < epos; n += 256) m = fmaxf(m, gate[n]);
    red[t] = m;
    __syncthreads();
    for (int o = 128; o; o >>= 1) {
        if (t < o) red[t] = fmaxf(red[t], red[t + o]);
        __syncthreads();
    }
    float mval = red[0];
    __syncthreads();
    float sum = 0.f;
    for (int n = s + t; n < epos; n += 256) sum += expf(gate[n] - mval);
    red[t] = sum;
    __syncthreads();
    for (int o = 128; o; o >>= 1) {
        if (t < o) red[t] += red[t + o];
        __syncthreads();
    }
    float ssum = red[0];
    __syncthreads();
    float acc = 0.f;
    for (int base = s; base < epos; base += 256) {
        int n = base + t;
        wn[t] = (n < epos) ? expf(gate[n] - mval) : 0.f;
        __syncthreads();
        int cnt = min(256, epos - base);
        for (int j = 0; j < cnt; j++) acc += wn[j] * h3[(size_t)(base + j) * CC + t];
        __syncthreads();
    }
    graph[b * CC + t] = acc / (ssum + 1e-16f);
}

__global__ void proj_kernel(const float* __restrict__ graph, const float* __restrict__ pw,
                            const float* __restrict__ pb, float* __restrict__ out) {
    __shared__ float g[256];
    int b = blockIdx.x, t = threadIdx.x;
    g[t] = graph[b * CC + t];
    __syncthreads();
    for (int j = t; j < 1024; j += 256) {
        float acc = pb[j];
        for (int c = 0; c < 256; c++) acc += g[c] * pw[c * 1024 + j];
        out[(size_t)b * 1024 + j] = acc;
    }
}

// ---------------- host ----------------
extern "C" void kernel_launch(void* const* d_in, const int* in_sizes, int n_in,
                              void* d_out, int out_size, void* d_ws, size_t ws_size,
                              hipStream_t stream) {
    const float* x = (const float*)d_in[0];
    const int* ei = (const int*)d_in[1];
    const float* ea = (const float*)d_in[2];
    const int* batch = (const int*)d_in[3];
    const float* w0 = (const float*)d_in[4];
    const float* w_rest = (const float*)d_in[5];
    const float* w_edge = (const float*)d_in[6];
    const float* att_src = (const float*)d_in[7];
    const float* att_dst = (const float*)d_in[8];
    const float* att_edge = (const float*)d_in[9];
    const float* bias012 = (const float*)d_in[10];
    const float* bias3 = (const float*)d_in[11];
    const float* bn_g = (const float*)d_in[12];
    const float* bn_b = (const float*)d_in[13];
    const float* bn_m = (const float*)d_in[14];
    const float* bn_v = (const float*)d_in[15];
    const float* gate_w = (const float*)d_in[16];
    const float* gate_b = (const float*)d_in[17];
    const float* proj_w = (const float*)d_in[18];
    const float* proj_b = (const float*)d_in[19];
    float* out = (float*)d_out;

    float* ws = (float*)d_ws;
    size_t off = 0;
    float* h_a = ws + off; off += (size_t)NN * HC;
    float* h_b = ws + off; off += (size_t)NN * HC;
    float* p_e = ws + off; off += (size_t)EE * 4;   // raw alpha, then p
    float* asrc = ws + off; off += (size_t)NN * 4;
    float* adst = ws + off; off += (size_t)NN * 4;
    float* self_raw = ws + off; off += (size_t)NN * 4;
    float* amax = ws + off; off += (size_t)NN * 4;
    float* denom = ws + off; off += (size_t)NN * 4;
    float* p_self = ws + off; off += (size_t)NN * 4;
    float* gate = ws + off; off += (size_t)NN;
    float* graph = ws + off; off += (size_t)BB * CC;
    float* ea_sums = ws + off; off += 4;
    float* Mmat = ws + off; off += 12;
    float* ae_self = ws + off; off += 4;
    int* counts = (int*)(ws + off); off += NN;
    int* indptr = (int*)(ws + off); off += NN + 1;
    int* fill = (int*)(ws + off); off += NN;
    int* sorted = (int*)(ws + off); off += EE;
    int* bptr = (int*)(ws + off); off += BB + 1;

    hipMemsetAsync(ea_sums, 0, 4 * sizeof(float), stream);
    hipMemsetAsync(counts, 0, NN * sizeof(int), stream);
    hipMemsetAsync(fill, 0, NN * sizeof(int), stream);

    ea_sum_kernel<<<64, 256, 0, stream>>>(ea, ea_sums, EE);
    hist_kernel<<<(EE + 255) / 256, 256, 0, stream>>>(ei, counts, EE);
    scan_kernel<<<1, 1024, 0, stream>>>(counts, indptr, NN);
    scatter_kernel<<<(EE + 255) / 256, 256, 0, stream>>>(ei, indptr, fill, sorted, EE);
    bptr_kernel<<<(NN + 255) / 256, 256, 0, stream>>>(batch, bptr, NN, BB);

    for (int i = 0; i < 4; i++) {
        if (i == 0) {
            gemm7_kernel<<<dim3(NN, 4), 256, 0, stream>>>(x, w0, h_a);
        } else {
            sgemm_kernel<<<dim3(HC / BN, (NN + BM - 1) / BM), 256, 0, stream>>>(
                h_b, w_rest + (size_t)(i - 1) * HC * HC, h_a, NN, HC, HC);
        }
        mmat_kernel<<<1, 256, 0, stream>>>(w_edge, att_edge, ea_sums, Mmat, ae_self, i,
                                           1.0f / EE);
        alpha_kernel<<<NN, 256, 0, stream>>>(h_a, att_src, att_dst, asrc, adst, i);
        self_kernel<<<(NN + 255) / 256, 256, 0, stream>>>(asrc, adst, ae_self, self_raw, amax);
        edge_raw_kernel<<<(EE + 255) / 256, 256, 0, stream>>>(ei, ea, Mmat, asrc, adst, p_e,
                                                              amax);
        self2_kernel<<<(NN + 255) / 256, 256, 0, stream>>>(self_raw, amax, p_self, denom);
        edge_p_kernel<<<(EE + 255) / 256, 256, 0, stream>>>(ei, p_e, amax, denom);
        agg_kernel<<<NN, 256, 0, stream>>>(h_a, p_e, p_self, denom, indptr, sorted, ei,
                                           bias012, bias3, bn_g, bn_b, bn_m, bn_v, h_b, i,
                                           (i < 3) ? 1 : 0);
    }

    gate_kernel<<<(NN + 3) / 4, 256, 0, stream>>>(h_b, gate_w, gate_b, gate);
    graphagg_kernel<<<BB, 256, 0, stream>>>(gate, h_b, bptr, graph);
    proj_kernel<<<BB, 256, 0, stream>>>(graph, proj_w, proj_b, out);
}

// Round 2
// 1059.767 us; speedup vs baseline: 2.1079x; 2.1079x over previous
//
#include <hip/hip_runtime.h>
#include <math.h>

#define NN 20000
#define EE 60000
#define BB 512
#define HC 1024
#define HH 4
#define CC 256

typedef _Float16 f16;
typedef f16 half8 __attribute__((ext_vector_type(8)));
typedef f16 f16x4 __attribute__((ext_vector_type(4)));
typedef float floatx4 __attribute__((ext_vector_type(4)));

// ---------------- helpers ----------------
__device__ __forceinline__ void atomicMaxF(float* addr, float val) {
    int* ia = (int*)addr;
    int old = *ia;
    while (__int_as_float(old) < val) {
        int assumed = old;
        old = atomicCAS(ia, assumed, __float_as_int(val));
        if (old == assumed) break;
    }
}

__device__ __forceinline__ void load_lds16(const void* g, void* l) {
    __builtin_amdgcn_global_load_lds((const __attribute__((address_space(1))) void*)g,
                                     (__attribute__((address_space(3))) void*)l, 16, 0, 0);
}

// ---------------- precompute kernels ----------------
__global__ void ea_sum_kernel(const float* __restrict__ ea, float* sums, int E_) {
    float s0 = 0.f, s1 = 0.f, s2 = 0.f;
    for (int e = blockIdx.x * 256 + threadIdx.x; e < E_; e += gridDim.x * 256) {
        s0 += ea[e * 3 + 0];
        s1 += ea[e * 3 + 1];
        s2 += ea[e * 3 + 2];
    }
    for (int o = 32; o; o >>= 1) {
        s0 += __shfl_down(s0, o);
        s1 += __shfl_down(s1, o);
        s2 += __shfl_down(s2, o);
    }
    if ((threadIdx.x & 63) == 0) {
        atomicAdd(&sums[0], s0);
        atomicAdd(&sums[1], s1);
        atomicAdd(&sums[2], s2);
    }
}

__global__ void hist_kernel(const int* __restrict__ ei, int* counts, int E_) {
    int e = blockIdx.x * 256 + threadIdx.x;
    if (e < E_) atomicAdd(&counts[ei[E_ + e]], 1);
}

__global__ void scan_kernel(const int* __restrict__ counts, int* indptr, int n) {
    __shared__ int sdata[1024];
    int t = threadIdx.x;
    int carry = 0;
    if (t == 0) indptr[0] = 0;
    for (int base = 0; base < n; base += 1024) {
        int i = base + t;
        int v = (i < n) ? counts[i] : 0;
        sdata[t] = v;
        __syncthreads();
        for (int off = 1; off < 1024; off <<= 1) {
            int tmp = (t >= off) ? sdata[t - off] : 0;
            __syncthreads();
            sdata[t] += tmp;
            __syncthreads();
        }
        if (i < n) indptr[i + 1] = carry + sdata[t];
        int total = sdata[1023];
        __syncthreads();
        carry += total;
    }
}

__global__ void scatter_kernel(const int* __restrict__ ei, const int* __restrict__ indptr,
                               int* fill, int* sorted, int E_) {
    int e = blockIdx.x * 256 + threadIdx.x;
    if (e >= E_) return;
    int d = ei[E_ + e];
    int pos = indptr[d] + atomicAdd(&fill[d], 1);
    sorted[pos] = e;
}

__global__ void bptr_kernel(const int* __restrict__ batch, int* bptr, int n, int nb) {
    int i = blockIdx.x * 256 + threadIdx.x;
    if (i >= n) return;
    int b = batch[i];
    if (i == 0) {
        for (int bb = 0; bb <= b; bb++) bptr[bb] = 0;
    } else {
        int pb = batch[i - 1];
        if (pb != b) {
            for (int bb = pb + 1; bb <= b; bb++) bptr[bb] = i;
        }
    }
    if (i == n - 1) {
        for (int bb = b + 1; bb <= nb; bb++) bptr[bb] = n;
    }
}

// transpose+convert w_rest[3][1024][1024] fp32 -> wt[3][n=1024][k=1024] fp16 (B^T)
__global__ void wconv_kernel(const float* __restrict__ w_rest, f16* __restrict__ wt) {
    __shared__ float tile[64][65];
    int l = blockIdx.z;
    int bx = blockIdx.x * 64;  // n base
    int by = blockIdx.y * 64;  // k base
    int t = threadIdx.x;
    int tr = t >> 6, tc = t & 63;
#pragma unroll
    for (int i = 0; i < 16; i++) {
        int r = by + i * 4 + tr;
        tile[i * 4 + tr][tc] = w_rest[(size_t)l * 1048576 + (size_t)r * 1024 + bx + tc];
    }
    __syncthreads();
#pragma unroll
    for (int i = 0; i < 16; i++) {
        int n = bx + i * 4 + tr;
        wt[(size_t)l * 1048576 + (size_t)n * 1024 + by + tc] = (f16)tile[tc][i * 4 + tr];
    }
}

// ---------------- GEMMs ----------------
// layer 0: h = x @ w0, K=7 (fp32, tiny K)
__global__ void gemm7_kernel(const float* __restrict__ x, const float* __restrict__ w0,
                             float* __restrict__ h) {
    int n = blockIdx.x;
    int j = blockIdx.y * 256 + threadIdx.x;
    float acc = 0.f;
#pragma unroll
    for (int f = 0; f < 7; f++) acc += x[n * 7 + f] * w0[f * HC + j];
    h[(size_t)n * HC + j] = acc;
}

// layers 1-3: C[M,N] = A[M,K] @ B[K,N] where Bt = B^T [N][K], fp16 in / fp32 out.
// 128x128 tile, BK=32, 4 waves (2x2), each wave 64x64 via 4x4 of 16x16x32 MFMA.
// LDS layout [kgroup 0..3][row 0..127][8 f16] => staging offset == tid*16B (global_load_lds-
// compatible) and frag ds_read_b128 is only 2-way bank-aliased (free, m136).
__global__ __launch_bounds__(256) void mfma_gemm_kernel(const f16* __restrict__ A,
                                                        const f16* __restrict__ Bt,
                                                        float* __restrict__ C,
                                                        int M, int N, int K) {
    __shared__ f16 As[4 * 128 * 8];
    __shared__ f16 Bs[4 * 128 * 8];
    int t = threadIdx.x;
    int wave = t >> 6, lane = t & 63;
    int wr = (wave >> 1) * 64;  // wave row origin in tile
    int wc = (wave & 1) * 64;   // wave col origin in tile
    int m0 = blockIdx.y * 128;
    int n0 = blockIdx.x * 128;

    floatx4 acc[4][4];
#pragma unroll
    for (int i = 0; i < 4; i++)
#pragma unroll
        for (int j = 0; j < 4; j++) acc[i][j] = (floatx4){0.f, 0.f, 0.f, 0.f};

    // staging: issue0 idx=t, issue1 idx=256+t; q=idx>>7, r=idx&127; LDS off = idx*16B
    int q0 = t >> 7, r0 = t & 127;
    int q1 = (256 + t) >> 7, r1 = (256 + t) & 127;
    int ga0 = m0 + r0; ga0 = ga0 < M ? ga0 : M - 1;
    int ga1 = m0 + r1; ga1 = ga1 < M ? ga1 : M - 1;
    const f16* pa0 = A + (size_t)ga0 * K + q0 * 8;
    const f16* pa1 = A + (size_t)ga1 * K + q1 * 8;
    const f16* pb0 = Bt + (size_t)(n0 + r0) * K + q0 * 8;
    const f16* pb1 = Bt + (size_t)(n0 + r1) * K + q1 * 8;
    f16* la0 = As + (size_t)t * 8;
    f16* la1 = As + (size_t)(256 + t) * 8;
    f16* lb0 = Bs + (size_t)t * 8;
    f16* lb1 = Bs + (size_t)(256 + t) * 8;

    // frag offsets: row = lane&15, kgroup = lane>>4
    int fq = lane >> 4, fr = lane & 15;
    int aoff[4], boff[4];
#pragma unroll
    for (int i = 0; i < 4; i++) {
        aoff[i] = (fq * 128 + wr + i * 16 + fr) * 8;
        boff[i] = (fq * 128 + wc + i * 16 + fr) * 8;
    }

    for (int k0 = 0; k0 < K; k0 += 32) {
        __syncthreads();
        load_lds16(pa0 + k0, la0);
        load_lds16(pa1 + k0, la1);
        load_lds16(pb0 + k0, lb0);
        load_lds16(pb1 + k0, lb1);
        __syncthreads();
        half8 af[4], bf[4];
#pragma unroll
        for (int i = 0; i < 4; i++) af[i] = *(const half8*)&As[aoff[i]];
#pragma unroll
        for (int j = 0; j < 4; j++) bf[j] = *(const half8*)&Bs[boff[j]];
#pragma unroll
        for (int i = 0; i < 4; i++)
#pragma unroll
            for (int j = 0; j < 4; j++)
                acc[i][j] = __builtin_amdgcn_mfma_f32_16x16x32_f16(af[i], bf[j], acc[i][j],
                                                                   0, 0, 0);
    }

    // C/D layout: col = lane&15, row = (lane>>4)*4 + reg  [m89, dtype-independent]
    int cr = lane >> 4, cc = lane & 15;
#pragma unroll
    for (int i = 0; i < 4; i++) {
#pragma unroll
        for (int r = 0; r < 4; r++) {
            int row = m0 + wr + i * 16 + cr * 4 + r;
            if (row < M) {
#pragma unroll
                for (int j = 0; j < 4; j++) {
                    C[(size_t)row * N + n0 + wc + j * 16 + cc] = acc[i][j][r];
                }
            }
        }
    }
}

// ---------------- attention kernels ----------------
__global__ void mmat_kernel(const float* __restrict__ w_edge, const float* __restrict__ att_edge,
                            const float* __restrict__ ea_sums, float* Mmat, float* ae_self,
                            int layer, float invE) {
    __shared__ float red[256];
    __shared__ float Ms[12];
    int t = threadIdx.x;
    for (int dh = 0; dh < 12; dh++) {
        int d = dh >> 2, hh = dh & 3;
        float v = w_edge[layer * 3072 + d * HC + hh * CC + t] *
                  att_edge[layer * HC + hh * CC + t];
        red[t] = v;
        __syncthreads();
        for (int o = 128; o; o >>= 1) {
            if (t < o) red[t] += red[t + o];
            __syncthreads();
        }
        if (t == 0) {
            Ms[dh] = red[0];
            Mmat[dh] = red[0];
        }
        __syncthreads();
    }
    if (t < 4) {
        float v = 0.f;
        for (int d = 0; d < 3; d++) v += ea_sums[d] * invE * Ms[d * 4 + t];
        ae_self[t] = v;
    }
}

__global__ void alpha_kernel(const float* __restrict__ h, const float* __restrict__ att_src,
                             const float* __restrict__ att_dst, float* asrc, float* adst,
                             int layer) {
    int n = blockIdx.x;
    int t = threadIdx.x;
    int w = t >> 6, lane = t & 63;
    const float4 hv = *(const float4*)&h[(size_t)n * HC + w * CC + lane * 4];
    const float4 s4 = *(const float4*)&att_src[layer * HC + w * CC + lane * 4];
    const float4 d4 = *(const float4*)&att_dst[layer * HC + w * CC + lane * 4];
    float ss = hv.x * s4.x + hv.y * s4.y + hv.z * s4.z + hv.w * s4.w;
    float sd = hv.x * d4.x + hv.y * d4.y + hv.z * d4.z + hv.w * d4.w;
    for (int o = 32; o; o >>= 1) {
        ss += __shfl_down(ss, o);
        sd += __shfl_down(sd, o);
    }
    if (lane == 0) {
        asrc[n * 4 + w] = ss;
        adst[n * 4 + w] = sd;
    }
}

__global__ void self_kernel(const float* __restrict__ asrc, const float* __restrict__ adst,
                            const float* __restrict__ ae_self, float* self_raw, float* amax) {
    int n = blockIdx.x * 256 + threadIdx.x;
    if (n >= NN) return;
    float4 as4 = *(const float4*)&asrc[n * 4];
    float4 ad4 = *(const float4*)&adst[n * 4];
    float r[4];
    r[0] = as4.x + ad4.x + ae_self[0];
    r[1] = as4.y + ad4.y + ae_self[1];
    r[2] = as4.z + ad4.z + ae_self[2];
    r[3] = as4.w + ad4.w + ae_self[3];
#pragma unroll
    for (int k = 0; k < 4; k++) r[k] = (r[k] > 0.f) ? r[k] : 0.2f * r[k];
    *(float4*)&self_raw[n * 4] = make_float4(r[0], r[1], r[2], r[3]);
    *(float4*)&amax[n * 4] = make_float4(r[0], r[1], r[2], r[3]);
}

__global__ void edge_raw_kernel(const int* __restrict__ ei, const float* __restrict__ ea,
                                const float* __restrict__ Mmat, const float* __restrict__ asrc,
                                const float* __restrict__ adst, float* raw, float* amax) {
    int e = blockIdx.x * 256 + threadIdx.x;
    if (e >= EE) return;
    int s = ei[e], d = ei[EE + e];
    float a0 = ea[e * 3 + 0], a1 = ea[e * 3 + 1], a2 = ea[e * 3 + 2];
    float4 as4 = *(const float4*)&asrc[s * 4];
    float4 ad4 = *(const float4*)&adst[d * 4];
    float asl[4] = {as4.x, as4.y, as4.z, as4.w};
    float adl[4] = {ad4.x, ad4.y, ad4.z, ad4.w};
#pragma unroll
    for (int h = 0; h < 4; h++) {
        float aeh = a0 * Mmat[h] + a1 * Mmat[4 + h] + a2 * Mmat[8 + h];
        float r = asl[h] + adl[h] + aeh;
        r = (r > 0.f) ? r : 0.2f * r;
        raw[e * 4 + h] = r;
        atomicMaxF(&amax[d * 4 + h], r);
    }
}

__global__ void self2_kernel(const float* __restrict__ self_raw, const float* __restrict__ amax,
                             float* p_self, float* denom) {
    int n = blockIdx.x * 256 + threadIdx.x;
    if (n >= NN) return;
    float4 sr = *(const float4*)&self_raw[n * 4];
    float4 am = *(const float4*)&amax[n * 4];
    float4 p;
    p.x = expf(sr.x - am.x);
    p.y = expf(sr.y - am.y);
    p.z = expf(sr.z - am.z);
    p.w = expf(sr.w - am.w);
    *(float4*)&p_self[n * 4] = p;
    *(float4*)&denom[n * 4] = p;
}

__global__ void edge_p_kernel(const int* __restrict__ ei, float* raw_p,
                              const float* __restrict__ amax, float* denom) {
    int e = blockIdx.x * 256 + threadIdx.x;
    if (e >= EE) return;
    int d = ei[EE + e];
#pragma unroll
    for (int h = 0; h < 4; h++) {
        float p = expf(raw_p[e * 4 + h] - amax[d * 4 + h]);
        raw_p[e * 4 + h] = p;
        atomicAdd(&denom[d * 4 + h], p);
    }
}

// aggregation: concat layers write fp16 (next GEMM input); layer 3 writes fp32 head-mean
__global__ void agg_kernel(const float* __restrict__ h_lin, const float* __restrict__ p_e,
                           const float* __restrict__ p_self, const float* __restrict__ denom,
                           const int* __restrict__ indptr, const int* __restrict__ sorted,
                           const int* __restrict__ ei, const float* __restrict__ bias012,
                           const float* __restrict__ bias3, const float* __restrict__ bn_g,
                           const float* __restrict__ bn_b, const float* __restrict__ bn_m,
                           const float* __restrict__ bn_v, f16* __restrict__ out16,
                           float* __restrict__ out3, int layer, int concat) {
    __shared__ float buf[1024];
    int n = blockIdx.x, t = threadIdx.x;
    int h = t >> 6;
    int c4 = t * 4;
    float ax = 0.f, ay = 0.f, az = 0.f, aw = 0.f;
    int s = indptr[n], epos = indptr[n + 1];
    for (int idx = s; idx < epos; idx++) {
        int eid = sorted[idx];
        int sr = ei[eid];
        float pe = p_e[eid * 4 + h];
        const float4 v = *(const float4*)&h_lin[(size_t)sr * HC + c4];
        ax += pe * v.x; ay += pe * v.y; az += pe * v.z; aw += pe * v.w;
    }
    {
        float ps = p_self[n * 4 + h];
        const float4 v = *(const float4*)&h_lin[(size_t)n * HC + c4];
        ax += ps * v.x; ay += ps * v.y; az += ps * v.z; aw += ps * v.w;
    }
    float inv = 1.0f / (denom[n * 4 + h] + 1e-16f);
    ax *= inv; ay *= inv; az *= inv; aw *= inv;
    if (concat) {
        float vals[4] = {ax, ay, az, aw};
        f16x4 o;
#pragma unroll
        for (int k = 0; k < 4; k++) {
            int j = c4 + k;
            float val = vals[k] + bias012[layer * HC + j];
            float g = bn_g[layer * HC + j];
            float be = bn_b[layer * HC + j];
            float mu = bn_m[layer * HC + j];
            float va = bn_v[layer * HC + j];
            val = (val - mu) * (g * rsqrtf(va + 1e-5f)) + be;
            o[k] = (f16)fmaxf(val, 0.f);
        }
        *(f16x4*)&out16[(size_t)n * HC + c4] = o;
    } else {
        buf[c4 + 0] = ax;
        buf[c4 + 1] = ay;
        buf[c4 + 2] = az;
        buf[c4 + 3] = aw;
        __syncthreads();
        if (t < 64) {
#pragma unroll
            for (int k = 0; k < 4; k++) {
                int c = t * 4 + k;
                float v2 = 0.25f * (buf[c] + buf[256 + c] + buf[512 + c] + buf[768 + c]) +
                           bias3[c];
                out3[(size_t)n * CC + c] = v2;
            }
        }
    }
}

// ---------------- readout ----------------
__global__ void gate_kernel(const float* __restrict__ h3, const float* __restrict__ gw,
                            const float* __restrict__ gb, float* gate) {
    int node = blockIdx.x * 4 + (threadIdx.x >> 6);
    int lane = threadIdx.x & 63;
    if (node >= NN) return;
    const float4 hv = *(const float4*)&h3[(size_t)node * CC + lane * 4];
    const float4 w4 = *(const float4*)&gw[lane * 4];
    float s = hv.x * w4.x + hv.y * w4.y + hv.z * w4.z + hv.w * w4.w;
    for (int o = 32; o; o >>= 1) s += __shfl_down(s, o);
    if (lane == 0) gate[node] = s + gb[0];
}

__global__ void graphagg_kernel(const float* __restrict__ gate, const float* __restrict__ h3,
                                const int* __restrict__ bptr, float* __restrict__ graph) {
    __shared__ float red[256];
    __shared__ float wn[256];
    int b = blockIdx.x, t = threadIdx.x;
    int s = bptr[b], epos = bptr[b + 1];
    float m = -3.4e38f;
    for (int n = s + t; n < epos; n += 256) m = fmaxf(m, gate[n]);
    red[t] = m;
    __syncthreads();
    for (int o = 128; o; o >>= 1) {
        if (t < o) red[t] = fmaxf(red[t], red[t + o]);
        __syncthreads();
    }
    float mval = red[0];
    __syncthreads();
    float sum = 0.f;
    for (int n = s + t; n < epos; n += 256) sum += expf(gate[n] - mval);
    red[t] = sum;
    __syncthreads();
    for (int o = 128; o; o >>= 1) {
        if (t < o) red[t] += red[t + o];
        __syncthreads();
    }
    float ssum = red[0];
    __syncthreads();
    float acc = 0.f;
    for (int base = s; base < epos; base += 256) {
        int n = base + t;
        wn[t] = (n < epos) ? expf(gate[n] - mval) : 0.f;
        __syncthreads();
        int cnt = min(256, epos - base);
        for (int j = 0; j < cnt; j++) acc += wn[j] * h3[(size_t)(base + j) * CC + t];
        __syncthreads();
    }
    graph[b * CC + t] = acc / (ssum + 1e-16f);
}

__global__ void proj_kernel(const float* __restrict__ graph, const float* __restrict__ pw,
                            const float* __restrict__ pb, float* __restrict__ out) {
    __shared__ float g[256];
    int b = blockIdx.x, t = threadIdx.x;
    g[t] = graph[b * CC + t];
    __syncthreads();
    for (int j = t; j < 1024; j += 256) {
        float acc = pb[j];
        for (int c = 0; c < 256; c++) acc += g[c] * pw[c * 1024 + j];
        out[(size_t)b * 1024 + j] = acc;
    }
}

// ---------------- host ----------------
extern "C" void kernel_launch(void* const* d_in, const int* in_sizes, int n_in,
                              void* d_out, int out_size, void* d_ws, size_t ws_size,
                              hipStream_t stream) {
    const float* x = (const float*)d_in[0];
    const int* ei = (const int*)d_in[1];
    const float* ea = (const float*)d_in[2];
    const int* batch = (const int*)d_in[3];
    const float* w0 = (const float*)d_in[4];
    const float* w_rest = (const float*)d_in[5];
    const float* w_edge = (const float*)d_in[6];
    const float* att_src = (const float*)d_in[7];
    const float* att_dst = (const float*)d_in[8];
    const float* att_edge = (const float*)d_in[9];
    const float* bias012 = (const float*)d_in[10];
    const float* bias3 = (const float*)d_in[11];
    const float* bn_g = (const float*)d_in[12];
    const float* bn_b = (const float*)d_in[13];
    const float* bn_m = (const float*)d_in[14];
    const float* bn_v = (const float*)d_in[15];
    const float* gate_w = (const float*)d_in[16];
    const float* gate_b = (const float*)d_in[17];
    const float* proj_w = (const float*)d_in[18];
    const float* proj_b = (const float*)d_in[19];
    float* out = (float*)d_out;

    float* ws = (float*)d_ws;
    size_t off = 0;
    float* h_a = ws + off; off += (size_t)NN * HC;          // fp32 GEMM output
    f16* h_bf = (f16*)(ws + off); off += (size_t)NN * HC / 2;  // fp16 GEMM input
    float* h3 = ws + off; off += (size_t)NN * CC;           // layer-3 output
    f16* wt = (f16*)(ws + off); off += (size_t)3 * HC * HC / 2; // W^T fp16
    float* p_e = ws + off; off += (size_t)EE * 4;
    float* asrc = ws + off; off += (size_t)NN * 4;
    float* adst = ws + off; off += (size_t)NN * 4;
    float* self_raw = ws + off; off += (size_t)NN * 4;
    float* amax = ws + off; off += (size_t)NN * 4;
    float* denom = ws + off; off += (size_t)NN * 4;
    float* p_self = ws + off; off += (size_t)NN * 4;
    float* gate = ws + off; off += (size_t)NN;
    float* graph = ws + off; off += (size_t)BB * CC;
    float* ea_sums = ws + off; off += 4;
    float* Mmat = ws + off; off += 12;
    float* ae_self = ws + off; off += 4;
    int* counts = (int*)(ws + off); off += NN;
    int* indptr = (int*)(ws + off); off += NN + 1;
    int* fill = (int*)(ws + off); off += NN;
    int* sorted = (int*)(ws + off); off += EE;
    int* bptr = (int*)(ws + off); off += BB + 1;

    hipMemsetAsync(ea_sums, 0, 4 * sizeof(float), stream);
    hipMemsetAsync(counts, 0, NN * sizeof(int), stream);
    hipMemsetAsync(fill, 0, NN * sizeof(int), stream);

    ea_sum_kernel<<<64, 256, 0, stream>>>(ea, ea_sums, EE);
    hist_kernel<<<(EE + 255) / 256, 256, 0, stream>>>(ei, counts, EE);
    scan_kernel<<<1, 1024, 0, stream>>>(counts, indptr, NN);
    scatter_kernel<<<(EE + 255) / 256, 256, 0, stream>>>(ei, indptr, fill, sorted, EE);
    bptr_kernel<<<(NN + 255) / 256, 256, 0, stream>>>(batch, bptr, NN, BB);
    wconv_kernel<<<dim3(16, 16, 3), 256, 0, stream>>>(w_rest, wt);

    for (int i = 0; i < 4; i++) {
        if (i == 0) {
            gemm7_kernel<<<dim3(NN, 4), 256, 0, stream>>>(x, w0, h_a);
        } else {
            mfma_gemm_kernel<<<dim3(HC / 128, (NN + 127) / 128), 256, 0, stream>>>(
                h_bf, wt + (size_t)(i - 1) * HC * HC, h_a, NN, HC, HC);
        }
        mmat_kernel<<<1, 256, 0, stream>>>(w_edge, att_edge, ea_sums, Mmat, ae_self, i,
                                           1.0f / EE);
        alpha_kernel<<<NN, 256, 0, stream>>>(h_a, att_src, att_dst, asrc, adst, i);
        self_kernel<<<(NN + 255) / 256, 256, 0, stream>>>(asrc, adst, ae_self, self_raw, amax);
        edge_raw_kernel<<<(EE + 255) / 256, 256, 0, stream>>>(ei, ea, Mmat, asrc, adst, p_e,
                                                              amax);
        self2_kernel<<<(NN + 255) / 256, 256, 0, stream>>>(self_raw, amax, p_self, denom);
        edge_p_kernel<<<(EE + 255) / 256, 256, 0, stream>>>(ei, p_e, amax, denom);
        agg_kernel<<<NN, 256, 0, stream>>>(h_a, p_e, p_self, denom, indptr, sorted, ei,
                                           bias012, bias3, bn_g, bn_b, bn_m, bn_v, h_bf, h3,
                                           i, (i < 3) ? 1 : 0);
    }

    gate_kernel<<<(NN + 3) / 4, 256, 0, stream>>>(h3, gate_w, gate_b, gate);
    graphagg_kernel<<<BB, 256, 0, stream>>>(gate, h3, bptr, graph);
    proj_kernel<<<BB, 256, 0, stream>>>(graph, proj_w, proj_b, out);
}

// Round 3
// 909.173 us; speedup vs baseline: 2.4570x; 1.1656x over previous
//
#include <hip/hip_runtime.h>
#include <math.h>

#define NN 20000
#define EE 60000
#define BB 512
#define HC 1024
#define HH 4
#define CC 256

typedef _Float16 f16;
typedef f16 half8 __attribute__((ext_vector_type(8)));
typedef f16 f16x4 __attribute__((ext_vector_type(4)));
typedef float floatx4 __attribute__((ext_vector_type(4)));

__device__ __forceinline__ void load_lds16(const void* g, void* l) {
    __builtin_amdgcn_global_load_lds((const __attribute__((address_space(1))) void*)g,
                                     (__attribute__((address_space(3))) void*)l, 16, 0, 0);
}

// ---------------- precompute kernels ----------------
__global__ void ea_sum_kernel(const float* __restrict__ ea, float* sums, int E_) {
    float s0 = 0.f, s1 = 0.f, s2 = 0.f;
    for (int e = blockIdx.x * 256 + threadIdx.x; e < E_; e += gridDim.x * 256) {
        s0 += ea[e * 3 + 0];
        s1 += ea[e * 3 + 1];
        s2 += ea[e * 3 + 2];
    }
    for (int o = 32; o; o >>= 1) {
        s0 += __shfl_down(s0, o);
        s1 += __shfl_down(s1, o);
        s2 += __shfl_down(s2, o);
    }
    if ((threadIdx.x & 63) == 0) {
        atomicAdd(&sums[0], s0);
        atomicAdd(&sums[1], s1);
        atomicAdd(&sums[2], s2);
    }
}

__global__ void hist_kernel(const int* __restrict__ ei, int* counts, int E_) {
    int e = blockIdx.x * 256 + threadIdx.x;
    if (e < E_) atomicAdd(&counts[ei[E_ + e]], 1);
}

__global__ void scan_kernel(const int* __restrict__ counts, int* indptr, int n) {
    __shared__ int sdata[1024];
    int t = threadIdx.x;
    int carry = 0;
    if (t == 0) indptr[0] = 0;
    for (int base = 0; base < n; base += 1024) {
        int i = base + t;
        int v = (i < n) ? counts[i] : 0;
        sdata[t] = v;
        __syncthreads();
        for (int off = 1; off < 1024; off <<= 1) {
            int tmp = (t >= off) ? sdata[t - off] : 0;
            __syncthreads();
            sdata[t] += tmp;
            __syncthreads();
        }
        if (i < n) indptr[i + 1] = carry + sdata[t];
        int total = sdata[1023];
        __syncthreads();
        carry += total;
    }
}

__global__ void scatter_kernel(const int* __restrict__ ei, const int* __restrict__ indptr,
                               int* fill, int* sorted, int E_) {
    int e = blockIdx.x * 256 + threadIdx.x;
    if (e >= E_) return;
    int d = ei[E_ + e];
    int pos = indptr[d] + atomicAdd(&fill[d], 1);
    sorted[pos] = e;
}

__global__ void bptr_kernel(const int* __restrict__ batch, int* bptr, int n, int nb) {
    int i = blockIdx.x * 256 + threadIdx.x;
    if (i >= n) return;
    int b = batch[i];
    if (i == 0) {
        for (int bb = 0; bb <= b; bb++) bptr[bb] = 0;
    } else {
        int pb = batch[i - 1];
        if (pb != b) {
            for (int bb = pb + 1; bb <= b; bb++) bptr[bb] = i;
        }
    }
    if (i == n - 1) {
        for (int bb = b + 1; bb <= nb; bb++) bptr[bb] = n;
    }
}

// transpose+convert w_rest[3][1024][1024] fp32 -> wt[3][n][k] fp16 (B^T)
__global__ void wconv_kernel(const float* __restrict__ w_rest, f16* __restrict__ wt) {
    __shared__ float tile[64][65];
    int l = blockIdx.z;
    int bx = blockIdx.x * 64;
    int by = blockIdx.y * 64;
    int t = threadIdx.x;
    int tr = t >> 6, tc = t & 63;
#pragma unroll
    for (int i = 0; i < 16; i++) {
        int r = by + i * 4 + tr;
        tile[i * 4 + tr][tc] = w_rest[(size_t)l * 1048576 + (size_t)r * 1024 + bx + tc];
    }
    __syncthreads();
#pragma unroll
    for (int i = 0; i < 16; i++) {
        int n = bx + i * 4 + tr;
        wt[(size_t)l * 1048576 + (size_t)n * 1024 + by + tc] = (f16)tile[tc][i * 4 + tr];
    }
}

// Mmat[l][d][h] = sum_c We[l,d,h*C+c]*a_e[l,h,c]; ae_self[l][h] from mean edge attr
__global__ void mmat_all_kernel(const float* __restrict__ w_edge,
                                const float* __restrict__ att_edge,
                                const float* __restrict__ ea_sums, float* Mmat,
                                float* ae_self, float invE) {
    __shared__ float red[256];
    __shared__ float Ms[12];
    int l = blockIdx.x;
    int t = threadIdx.x;
    for (int dh = 0; dh < 12; dh++) {
        int d = dh >> 2, hh = dh & 3;
        float v = w_edge[l * 3072 + d * HC + hh * CC + t] * att_edge[l * HC + hh * CC + t];
        red[t] = v;
        __syncthreads();
        for (int o = 128; o; o >>= 1) {
            if (t < o) red[t] += red[t + o];
            __syncthreads();
        }
        if (t == 0) {
            Ms[dh] = red[0];
            Mmat[l * 12 + dh] = red[0];
        }
        __syncthreads();
    }
    if (t < 4) {
        float v = 0.f;
        for (int d = 0; d < 3; d++) v += ea_sums[d] * invE * Ms[d * 4 + t];
        ae_self[l * 4 + t] = v;
    }
}

// ---------------- GEMMs (fused alpha-dot epilogue) ----------------
// layer 0: h16 = x @ w0 (K=7) + asrc/adst (plain store: one block per (node,head))
__global__ void gemm7_kernel(const float* __restrict__ x, const float* __restrict__ w0,
                             const float* __restrict__ att_src,
                             const float* __restrict__ att_dst, f16* __restrict__ h16,
                             float* __restrict__ asrc, float* __restrict__ adst) {
    __shared__ float red[8];
    int n = blockIdx.x, head = blockIdx.y;
    int t = threadIdx.x;
    int j = head * 256 + t;
    float acc = 0.f;
#pragma unroll
    for (int f = 0; f < 7; f++) acc += x[n * 7 + f] * w0[f * HC + j];
    h16[(size_t)n * HC + j] = (f16)acc;
    float sp = acc * att_src[j];
    float dp = acc * att_dst[j];
    for (int m = 1; m < 64; m <<= 1) {
        sp += __shfl_xor(sp, m);
        dp += __shfl_xor(dp, m);
    }
    int wave = t >> 6, lane = t & 63;
    if (lane == 0) {
        red[wave * 2] = sp;
        red[wave * 2 + 1] = dp;
    }
    __syncthreads();
    if (t == 0) {
        asrc[n * 4 + head] = red[0] + red[2] + red[4] + red[6];
        adst[n * 4 + head] = red[1] + red[3] + red[5] + red[7];
    }
}

// layers 1-3: C16[M,N] = A16 @ Bt^T, fp16 in/out, fp32 acc.
// Epilogue also accumulates asrc/adst (per 128-col block = single head).
__global__ __launch_bounds__(256) void mfma_gemm_kernel(
    const f16* __restrict__ A, const f16* __restrict__ Bt, f16* __restrict__ C16,
    const float* __restrict__ att_src_l, const float* __restrict__ att_dst_l,
    float* __restrict__ asrc, float* __restrict__ adst, int M, int N, int K) {
    __shared__ f16 As[4 * 128 * 8];
    __shared__ f16 Bs[4 * 128 * 8];
    int t = threadIdx.x;
    int wave = t >> 6, lane = t & 63;
    int wr = (wave >> 1) * 64;
    int wc = (wave & 1) * 64;
    int m0 = blockIdx.y * 128;
    int n0 = blockIdx.x * 128;

    floatx4 acc[4][4];
#pragma unroll
    for (int i = 0; i < 4; i++)
#pragma unroll
        for (int j = 0; j < 4; j++) acc[i][j] = (floatx4){0.f, 0.f, 0.f, 0.f};

    int q0 = t >> 7, r0 = t & 127;
    int q1 = (256 + t) >> 7, r1 = (256 + t) & 127;
    int ga0 = m0 + r0; ga0 = ga0 < M ? ga0 : M - 1;
    int ga1 = m0 + r1; ga1 = ga1 < M ? ga1 : M - 1;
    const f16* pa0 = A + (size_t)ga0 * K + q0 * 8;
    const f16* pa1 = A + (size_t)ga1 * K + q1 * 8;
    const f16* pb0 = Bt + (size_t)(n0 + r0) * K + q0 * 8;
    const f16* pb1 = Bt + (size_t)(n0 + r1) * K + q1 * 8;
    f16* la0 = As + (size_t)t * 8;
    f16* la1 = As + (size_t)(256 + t) * 8;
    f16* lb0 = Bs + (size_t)t * 8;
    f16* lb1 = Bs + (size_t)(256 + t) * 8;

    int fq = lane >> 4, fr = lane & 15;
    int aoff[4], boff[4];
#pragma unroll
    for (int i = 0; i < 4; i++) {
        aoff[i] = (fq * 128 + wr + i * 16 + fr) * 8;
        boff[i] = (fq * 128 + wc + i * 16 + fr) * 8;
    }

    for (int k0 = 0; k0 < K; k0 += 32) {
        __syncthreads();
        load_lds16(pa0 + k0, la0);
        load_lds16(pa1 + k0, la1);
        load_lds16(pb0 + k0, lb0);
        load_lds16(pb1 + k0, lb1);
        __syncthreads();
        half8 af[4], bf[4];
#pragma unroll
        for (int i = 0; i < 4; i++) af[i] = *(const half8*)&As[aoff[i]];
#pragma unroll
        for (int j = 0; j < 4; j++) bf[j] = *(const half8*)&Bs[boff[j]];
#pragma unroll
        for (int i = 0; i < 4; i++)
#pragma unroll
            for (int j = 0; j < 4; j++)
                acc[i][j] = __builtin_amdgcn_mfma_f32_16x16x32_f16(af[i], bf[j], acc[i][j],
                                                                   0, 0, 0);
    }

    // C/D layout: col = lane&15, row = (lane>>4)*4 + reg
    int cr = lane >> 4, cc = lane & 15;
    int head = n0 >> 8;  // 128-col block sits in one head
    float as_c[4], ad_c[4];
#pragma unroll
    for (int j = 0; j < 4; j++) {
        int col = n0 + wc + j * 16 + cc;
        as_c[j] = att_src_l[col];
        ad_c[j] = att_dst_l[col];
    }
#pragma unroll
    for (int i = 0; i < 4; i++) {
#pragma unroll
        for (int r = 0; r < 4; r++) {
            int row = m0 + wr + i * 16 + cr * 4 + r;
            float sp = 0.f, dp = 0.f;
#pragma unroll
            for (int j = 0; j < 4; j++) {
                float v = acc[i][j][r];
                sp += v * as_c[j];
                dp += v * ad_c[j];
            }
            for (int m = 1; m < 16; m <<= 1) {
                sp += __shfl_xor(sp, m);
                dp += __shfl_xor(dp, m);
            }
            if (row < M) {
                if (cc == 0) {
                    atomicAdd(&asrc[row * 4 + head], sp);
                    atomicAdd(&adst[row * 4 + head], dp);
                }
#pragma unroll
                for (int j = 0; j < 4; j++)
                    C16[(size_t)row * N + n0 + wc + j * 16 + cc] = (f16)acc[i][j][r];
            }
        }
    }
}

// ---------------- attention (single-pass softmax, no amax) ----------------
__global__ void self_kernel(const float* __restrict__ asrc, const float* __restrict__ adst,
                            const float* __restrict__ ae_self, float* p_self, float* denom,
                            int layer) {
    int n = blockIdx.x * 256 + threadIdx.x;
    if (n >= NN) return;
    float4 as4 = *(const float4*)&asrc[n * 4];
    float4 ad4 = *(const float4*)&adst[n * 4];
    float r[4];
    r[0] = as4.x + ad4.x + ae_self[layer * 4 + 0];
    r[1] = as4.y + ad4.y + ae_self[layer * 4 + 1];
    r[2] = as4.z + ad4.z + ae_self[layer * 4 + 2];
    r[3] = as4.w + ad4.w + ae_self[layer * 4 + 3];
    float4 p;
#pragma unroll
    for (int k = 0; k < 4; k++) {
        float v = (r[k] > 0.f) ? r[k] : 0.2f * r[k];
        (&p.x)[k] = __expf(v);
    }
    *(float4*)&p_self[n * 4] = p;
    *(float4*)&denom[n * 4] = p;
}

__global__ void edge_kernel(const int* __restrict__ ei, const float* __restrict__ ea,
                            const float* __restrict__ Mmat, const float* __restrict__ asrc,
                            const float* __restrict__ adst, float* p_e, float* denom,
                            int layer) {
    int e = blockIdx.x * 256 + threadIdx.x;
    if (e >= EE) return;
    int s = ei[e], d = ei[EE + e];
    float a0 = ea[e * 3 + 0], a1 = ea[e * 3 + 1], a2 = ea[e * 3 + 2];
    float4 as4 = *(const float4*)&asrc[s * 4];
    float4 ad4 = *(const float4*)&adst[d * 4];
    float asl[4] = {as4.x, as4.y, as4.z, as4.w};
    float adl[4] = {ad4.x, ad4.y, ad4.z, ad4.w};
    const float* Ml = Mmat + layer * 12;
#pragma unroll
    for (int h = 0; h < 4; h++) {
        float aeh = a0 * Ml[h] + a1 * Ml[4 + h] + a2 * Ml[8 + h];
        float r = asl[h] + adl[h] + aeh;
        r = (r > 0.f) ? r : 0.2f * r;
        float p = __expf(r);
        p_e[e * 4 + h] = p;
        atomicAdd(&denom[d * 4 + h], p);
    }
}

// aggregation: reads fp16 h rows; concat layers -> fp16 out (next GEMM input);
// layer 3 -> fp32 head-mean
__global__ void agg_kernel(const f16* __restrict__ h16, const float* __restrict__ p_e,
                           const float* __restrict__ p_self, const float* __restrict__ denom,
                           const int* __restrict__ indptr, const int* __restrict__ sorted,
                           const int* __restrict__ ei, const float* __restrict__ bias012,
                           const float* __restrict__ bias3, const float* __restrict__ bn_g,
                           const float* __restrict__ bn_b, const float* __restrict__ bn_m,
                           const float* __restrict__ bn_v, f16* __restrict__ out16,
                           float* __restrict__ out3, int layer, int concat) {
    __shared__ float buf[1024];
    int n = blockIdx.x, t = threadIdx.x;
    int h = t >> 6;
    int c4 = t * 4;
    float ax = 0.f, ay = 0.f, az = 0.f, aw = 0.f;
    int s = indptr[n], epos = indptr[n + 1];
    for (int idx = s; idx < epos; idx++) {
        int eid = sorted[idx];
        int sr = ei[eid];
        float pe = p_e[eid * 4 + h];
        f16x4 v = *(const f16x4*)&h16[(size_t)sr * HC + c4];
        ax += pe * (float)v[0];
        ay += pe * (float)v[1];
        az += pe * (float)v[2];
        aw += pe * (float)v[3];
    }
    {
        float ps = p_self[n * 4 + h];
        f16x4 v = *(const f16x4*)&h16[(size_t)n * HC + c4];
        ax += ps * (float)v[0];
        ay += ps * (float)v[1];
        az += ps * (float)v[2];
        aw += ps * (float)v[3];
    }
    float inv = 1.0f / (denom[n * 4 + h] + 1e-16f);
    ax *= inv; ay *= inv; az *= inv; aw *= inv;
    if (concat) {
        float vals[4] = {ax, ay, az, aw};
        f16x4 o;
#pragma unroll
        for (int k = 0; k < 4; k++) {
            int j = c4 + k;
            float val = vals[k] + bias012[layer * HC + j];
            float g = bn_g[layer * HC + j];
            float be = bn_b[layer * HC + j];
            float mu = bn_m[layer * HC + j];
            float va = bn_v[layer * HC + j];
            val = (val - mu) * (g * rsqrtf(va + 1e-5f)) + be;
            o[k] = (f16)fmaxf(val, 0.f);
        }
        *(f16x4*)&out16[(size_t)n * HC + c4] = o;
    } else {
        buf[c4 + 0] = ax;
        buf[c4 + 1] = ay;
        buf[c4 + 2] = az;
        buf[c4 + 3] = aw;
        __syncthreads();
        if (t < 64) {
#pragma unroll
            for (int k = 0; k < 4; k++) {
                int c = t * 4 + k;
                float v2 = 0.25f * (buf[c] + buf[256 + c] + buf[512 + c] + buf[768 + c]) +
                           bias3[c];
                out3[(size_t)n * CC + c] = v2;
            }
        }
    }
}

// ---------------- readout ----------------
__global__ void gate_kernel(const float* __restrict__ h3, const float* __restrict__ gw,
                            const float* __restrict__ gb, float* gate) {
    int node = blockIdx.x * 4 + (threadIdx.x >> 6);
    int lane = threadIdx.x & 63;
    if (node >= NN) return;
    const float4 hv = *(const float4*)&h3[(size_t)node * CC + lane * 4];
    const float4 w4 = *(const float4*)&gw[lane * 4];
    float s = hv.x * w4.x + hv.y * w4.y + hv.z * w4.z + hv.w * w4.w;
    for (int o = 32; o; o >>= 1) s += __shfl_down(s, o);
    if (lane == 0) gate[node] = s + gb[0];
}

__global__ void graphagg_kernel(const float* __restrict__ gate, const float* __restrict__ h3,
                                const int* __restrict__ bptr, float* __restrict__ graph) {
    __shared__ float red[256];
    __shared__ float wn[256];
    int b = blockIdx.x, t = threadIdx.x;
    int s = bptr[b], epos = bptr[b + 1];
    float m = -3.4e38f;
    for (int n = s + t; n < epos; n += 256) m = fmaxf(m, gate[n]);
    red[t] = m;
    __syncthreads();
    for (int o = 128; o; o >>= 1) {
        if (t < o) red[t] = fmaxf(red[t], red[t + o]);
        __syncthreads();
    }
    float mval = red[0];
    __syncthreads();
    float sum = 0.f;
    for (int n = s + t; n < epos; n += 256) sum += __expf(gate[n] - mval);
    red[t] = sum;
    __syncthreads();
    for (int o = 128; o; o >>= 1) {
        if (t < o) red[t] += red[t + o];
        __syncthreads();
    }
    float ssum = red[0];
    __syncthreads();
    float acc = 0.f;
    for (int base = s; base < epos; base += 256) {
        int n = base + t;
        wn[t] = (n < epos) ? __expf(gate[n] - mval) : 0.f;
        __syncthreads();
        int cnt = min(256, epos - base);
        for (int j = 0; j < cnt; j++) acc += wn[j] * h3[(size_t)(base + j) * CC + t];
        __syncthreads();
    }
    graph[b * CC + t] = acc / (ssum + 1e-16f);
}

__global__ void proj_kernel(const float* __restrict__ graph, const float* __restrict__ pw,
                            const float* __restrict__ pb, float* __restrict__ out) {
    __shared__ float g[256];
    int b = blockIdx.x, t = threadIdx.x;
    g[t] = graph[b * CC + t];
    __syncthreads();
    for (int j = t; j < 1024; j += 256) {
        float acc = pb[j];
        for (int c = 0; c < 256; c++) acc += g[c] * pw[c * 1024 + j];
        out[(size_t)b * 1024 + j] = acc;
    }
}

// ---------------- host ----------------
extern "C" void kernel_launch(void* const* d_in, const int* in_sizes, int n_in,
                              void* d_out, int out_size, void* d_ws, size_t ws_size,
                              hipStream_t stream) {
    const float* x = (const float*)d_in[0];
    const int* ei = (const int*)d_in[1];
    const float* ea = (const float*)d_in[2];
    const int* batch = (const int*)d_in[3];
    const float* w0 = (const float*)d_in[4];
    const float* w_rest = (const float*)d_in[5];
    const float* w_edge = (const float*)d_in[6];
    const float* att_src = (const float*)d_in[7];
    const float* att_dst = (const float*)d_in[8];
    const float* att_edge = (const float*)d_in[9];
    const float* bias012 = (const float*)d_in[10];
    const float* bias3 = (const float*)d_in[11];
    const float* bn_g = (const float*)d_in[12];
    const float* bn_b = (const float*)d_in[13];
    const float* bn_m = (const float*)d_in[14];
    const float* bn_v = (const float*)d_in[15];
    const float* gate_w = (const float*)d_in[16];
    const float* gate_b = (const float*)d_in[17];
    const float* proj_w = (const float*)d_in[18];
    const float* proj_b = (const float*)d_in[19];
    float* out = (float*)d_out;

    float* ws = (float*)d_ws;
    size_t off = 0;
    f16* h_lin = (f16*)(ws + off); off += (size_t)NN * HC / 2;   // GEMM output (messages)
    f16* h_in = (f16*)(ws + off); off += (size_t)NN * HC / 2;    // agg output / GEMM input
    float* h3 = ws + off; off += (size_t)NN * CC;                // layer-3 output
    f16* wt = (f16*)(ws + off); off += (size_t)3 * HC * HC / 2;  // W^T fp16
    float* p_e = ws + off; off += (size_t)EE * 4;
    float* asrc = ws + off; off += (size_t)NN * 4;               // asrc+adst contiguous
    float* adst = ws + off; off += (size_t)NN * 4;
    float* denom = ws + off; off += (size_t)NN * 4;
    float* p_self = ws + off; off += (size_t)NN * 4;
    float* gate = ws + off; off += (size_t)NN;
    float* graph = ws + off; off += (size_t)BB * CC;
    float* ea_sums = ws + off; off += 4;
    float* Mmat = ws + off; off += 48;
    float* ae_self = ws + off; off += 16;
    int* counts = (int*)(ws + off); off += NN;
    int* indptr = (int*)(ws + off); off += NN + 1;
    int* fill = (int*)(ws + off); off += NN;
    int* sorted = (int*)(ws + off); off += EE;
    int* bptr = (int*)(ws + off); off += BB + 1;

    hipMemsetAsync(ea_sums, 0, 4 * sizeof(float), stream);
    hipMemsetAsync(counts, 0, NN * sizeof(int), stream);
    hipMemsetAsync(fill, 0, NN * sizeof(int), stream);

    ea_sum_kernel<<<64, 256, 0, stream>>>(ea, ea_sums, EE);
    hist_kernel<<<(EE + 255) / 256, 256, 0, stream>>>(ei, counts, EE);
    scan_kernel<<<1, 1024, 0, stream>>>(counts, indptr, NN);
    scatter_kernel<<<(EE + 255) / 256, 256, 0, stream>>>(ei, indptr, fill, sorted, EE);
    bptr_kernel<<<(NN + 255) / 256, 256, 0, stream>>>(batch, bptr, NN, BB);
    wconv_kernel<<<dim3(16, 16, 3), 256, 0, stream>>>(w_rest, wt);
    mmat_all_kernel<<<4, 256, 0, stream>>>(w_edge, att_edge, ea_sums, Mmat, ae_self,
                                           1.0f / EE);

    for (int i = 0; i < 4; i++) {
        if (i == 0) {
            gemm7_kernel<<<dim3(NN, 4), 256, 0, stream>>>(x, w0, att_src, att_dst, h_lin,
                                                          asrc, adst);
        } else {
            // zero asrc+adst (contiguous) before fused-epilogue atomics
            hipMemsetAsync(asrc, 0, (size_t)NN * 8 * sizeof(float), stream);
            mfma_gemm_kernel<<<dim3(HC / 128, (NN + 127) / 128), 256, 0, stream>>>(
                h_in, wt + (size_t)(i - 1) * HC * HC, h_lin, att_src + i * HC,
                att_dst + i * HC, asrc, adst, NN, HC, HC);
        }
        self_kernel<<<(NN + 255) / 256, 256, 0, stream>>>(asrc, adst, ae_self, p_self,
                                                          denom, i);
        edge_kernel<<<(EE + 255) / 256, 256, 0, stream>>>(ei, ea, Mmat, asrc, adst, p_e,
                                                          denom, i);
        agg_kernel<<<NN, 256, 0, stream>>>(h_lin, p_e, p_self, denom, indptr, sorted, ei,
                                           bias012, bias3, bn_g, bn_b, bn_m, bn_v, h_in, h3,
                                           i, (i < 3) ? 1 : 0);
    }

    gate_kernel<<<(NN + 3) / 4, 256, 0, stream>>>(h3, gate_w, gate_b, gate);
    graphagg_kernel<<<BB, 256, 0, stream>>>(gate, h3, bptr, graph);
    proj_kernel<<<BB, 256, 0, stream>>>(graph, proj_w, proj_b, out);
}

// Round 4
// 817.172 us; speedup vs baseline: 2.7336x; 1.1126x over previous
//
#include <hip/hip_runtime.h>
#include <math.h>

#define NN 20000
#define EE 60000
#define BB 512
#define HC 1024
#define HH 4
#define CC 256

typedef _Float16 f16;
typedef f16 half8 __attribute__((ext_vector_type(8)));
typedef f16 f16x4 __attribute__((ext_vector_type(4)));
typedef float floatx4 __attribute__((ext_vector_type(4)));

__device__ __forceinline__ void load_lds16(const void* g, void* l) {
    __builtin_amdgcn_global_load_lds((const __attribute__((address_space(1))) void*)g,
                                     (__attribute__((address_space(3))) void*)l, 16, 0, 0);
}

// ---------------- precompute kernels ----------------
__global__ void ea_sum_kernel(const float* __restrict__ ea, float* sums, int E_) {
    float s0 = 0.f, s1 = 0.f, s2 = 0.f;
    for (int e = blockIdx.x * 256 + threadIdx.x; e < E_; e += gridDim.x * 256) {
        s0 += ea[e * 3 + 0];
        s1 += ea[e * 3 + 1];
        s2 += ea[e * 3 + 2];
    }
    for (int o = 32; o; o >>= 1) {
        s0 += __shfl_down(s0, o);
        s1 += __shfl_down(s1, o);
        s2 += __shfl_down(s2, o);
    }
    if ((threadIdx.x & 63) == 0) {
        atomicAdd(&sums[0], s0);
        atomicAdd(&sums[1], s1);
        atomicAdd(&sums[2], s2);
    }
}

__global__ void hist_kernel(const int* __restrict__ ei, int* counts, int E_) {
    int e = blockIdx.x * 256 + threadIdx.x;
    if (e < E_) atomicAdd(&counts[ei[E_ + e]], 1);
}

__global__ void scan_kernel(const int* __restrict__ counts, int* indptr, int n) {
    __shared__ int sdata[1024];
    int t = threadIdx.x;
    int carry = 0;
    if (t == 0) indptr[0] = 0;
    for (int base = 0; base < n; base += 1024) {
        int i = base + t;
        int v = (i < n) ? counts[i] : 0;
        sdata[t] = v;
        __syncthreads();
        for (int off = 1; off < 1024; off <<= 1) {
            int tmp = (t >= off) ? sdata[t - off] : 0;
            __syncthreads();
            sdata[t] += tmp;
            __syncthreads();
        }
        if (i < n) indptr[i + 1] = carry + sdata[t];
        int total = sdata[1023];
        __syncthreads();
        carry += total;
    }
}

__global__ void scatter_kernel(const int* __restrict__ ei, const int* __restrict__ indptr,
                               int* fill, int* sorted, int E_) {
    int e = blockIdx.x * 256 + threadIdx.x;
    if (e >= E_) return;
    int d = ei[E_ + e];
    int pos = indptr[d] + atomicAdd(&fill[d], 1);
    sorted[pos] = e;
}

__global__ void bptr_kernel(const int* __restrict__ batch, int* bptr, int n, int nb) {
    int i = blockIdx.x * 256 + threadIdx.x;
    if (i >= n) return;
    int b = batch[i];
    if (i == 0) {
        for (int bb = 0; bb <= b; bb++) bptr[bb] = 0;
    } else {
        int pb = batch[i - 1];
        if (pb != b) {
            for (int bb = pb + 1; bb <= b; bb++) bptr[bb] = i;
        }
    }
    if (i == n - 1) {
        for (int bb = b + 1; bb <= nb; bb++) bptr[bb] = n;
    }
}

// transpose+convert w_rest[3][1024][1024] fp32 -> wt[3][n][k] fp16 (B^T)
__global__ void wconv_kernel(const float* __restrict__ w_rest, f16* __restrict__ wt) {
    __shared__ float tile[64][65];
    int l = blockIdx.z;
    int bx = blockIdx.x * 64;
    int by = blockIdx.y * 64;
    int t = threadIdx.x;
    int tr = t >> 6, tc = t & 63;
#pragma unroll
    for (int i = 0; i < 16; i++) {
        int r = by + i * 4 + tr;
        tile[i * 4 + tr][tc] = w_rest[(size_t)l * 1048576 + (size_t)r * 1024 + bx + tc];
    }
    __syncthreads();
#pragma unroll
    for (int i = 0; i < 16; i++) {
        int n = bx + i * 4 + tr;
        wt[(size_t)l * 1048576 + (size_t)n * 1024 + by + tc] = (f16)tile[tc][i * 4 + tr];
    }
}

// Mmat[l][d][h] = sum_c We[l,d,h*C+c]*a_e[l,h,c]; ae_self[l][h] from mean edge attr
__global__ void mmat_all_kernel(const float* __restrict__ w_edge,
                                const float* __restrict__ att_edge,
                                const float* __restrict__ ea_sums, float* Mmat,
                                float* ae_self, float invE) {
    __shared__ float red[256];
    __shared__ float Ms[12];
    int l = blockIdx.x;
    int t = threadIdx.x;
    for (int dh = 0; dh < 12; dh++) {
        int d = dh >> 2, hh = dh & 3;
        float v = w_edge[l * 3072 + d * HC + hh * CC + t] * att_edge[l * HC + hh * CC + t];
        red[t] = v;
        __syncthreads();
        for (int o = 128; o; o >>= 1) {
            if (t < o) red[t] += red[t + o];
            __syncthreads();
        }
        if (t == 0) {
            Ms[dh] = red[0];
            Mmat[l * 12 + dh] = red[0];
        }
        __syncthreads();
    }
    if (t < 4) {
        float v = 0.f;
        for (int d = 0; d < 3; d++) v += ea_sums[d] * invE * Ms[d * 4 + t];
        ae_self[l * 4 + t] = v;
    }
}

// wsv/wdv[l][k][hp] = sum_c w_rest[l][k][hp*256+c] * att_{src,dst}[l+1][hp*256+c]
__global__ void wvec_kernel(const float* __restrict__ w_rest, const float* __restrict__ att_src,
                            const float* __restrict__ att_dst, float* __restrict__ wsv,
                            float* __restrict__ wdv) {
    int l = blockIdx.y;   // 0..2 -> layer l+1
    int k = blockIdx.x;   // 0..1023
    int t = threadIdx.x;
    int hp = t >> 6, lane = t & 63;
    int col = hp * 256 + lane * 4;
    const float* wrow = w_rest + (size_t)l * 1048576 + (size_t)k * 1024;
    float4 w4 = *(const float4*)&wrow[col];
    float4 a4 = *(const float4*)&att_src[(l + 1) * HC + col];
    float4 d4 = *(const float4*)&att_dst[(l + 1) * HC + col];
    float sp = w4.x * a4.x + w4.y * a4.y + w4.z * a4.z + w4.w * a4.w;
    float dp = w4.x * d4.x + w4.y * d4.y + w4.z * d4.z + w4.w * d4.w;
    for (int m = 1; m < 64; m <<= 1) {
        sp += __shfl_xor(sp, m);
        dp += __shfl_xor(dp, m);
    }
    if (lane == 0) {
        wsv[((size_t)l * 1024 + k) * 4 + hp] = sp;
        wdv[((size_t)l * 1024 + k) * 4 + hp] = dp;
    }
}

// w0s/w0d[f][hp] = sum_c w0[f][hp*256+c] * att_{src,dst}[0][hp*256+c]
__global__ void w0vec_kernel(const float* __restrict__ w0, const float* __restrict__ att_src,
                             const float* __restrict__ att_dst, float* __restrict__ w0s,
                             float* __restrict__ w0d) {
    int f = blockIdx.x;  // 0..6
    int t = threadIdx.x;
    int hp = t >> 6, lane = t & 63;
    int col = hp * 256 + lane * 4;
    float4 w4 = *(const float4*)&w0[f * HC + col];
    float4 a4 = *(const float4*)&att_src[col];
    float4 d4 = *(const float4*)&att_dst[col];
    float sp = w4.x * a4.x + w4.y * a4.y + w4.z * a4.z + w4.w * a4.w;
    float dp = w4.x * d4.x + w4.y * d4.y + w4.z * d4.z + w4.w * d4.w;
    for (int m = 1; m < 64; m <<= 1) {
        sp += __shfl_xor(sp, m);
        dp += __shfl_xor(dp, m);
    }
    if (lane == 0) {
        w0s[f * 4 + hp] = sp;
        w0d[f * 4 + hp] = dp;
    }
}

// asrc0/adst0[n][hp] = x[n,:7] @ w0s/w0d
__global__ void alpha0_kernel(const float* __restrict__ x, const float* __restrict__ w0s,
                              const float* __restrict__ w0d, float* __restrict__ asrc,
                              float* __restrict__ adst) {
    int n = blockIdx.x * 256 + threadIdx.x;
    if (n >= NN) return;
    float xr[7];
#pragma unroll
    for (int f = 0; f < 7; f++) xr[f] = x[n * 7 + f];
#pragma unroll
    for (int hp = 0; hp < 4; hp++) {
        float s = 0.f, d = 0.f;
#pragma unroll
        for (int f = 0; f < 7; f++) {
            s += xr[f] * w0s[f * 4 + hp];
            d += xr[f] * w0d[f * 4 + hp];
        }
        asrc[n * 4 + hp] = s;
        adst[n * 4 + hp] = d;
    }
}

// ---------------- GEMMs ----------------
// layer 0: h16 = x @ w0 (K=7)
__global__ void gemm7_kernel(const float* __restrict__ x, const float* __restrict__ w0,
                             f16* __restrict__ h16) {
    int n = blockIdx.x;
    int j = blockIdx.y * 256 + threadIdx.x;
    float acc = 0.f;
#pragma unroll
    for (int f = 0; f < 7; f++) acc += x[n * 7 + f] * w0[f * HC + j];
    h16[(size_t)n * HC + j] = (f16)acc;
}

// layers 1-3: C16[M,N] = A16 @ Bt^T, fp16 in/out, fp32 acc. Pure-store epilogue.
__global__ __launch_bounds__(256) void mfma_gemm_kernel(const f16* __restrict__ A,
                                                        const f16* __restrict__ Bt,
                                                        f16* __restrict__ C16,
                                                        int M, int N, int K) {
    __shared__ f16 As[4 * 128 * 8];
    __shared__ f16 Bs[4 * 128 * 8];
    int t = threadIdx.x;
    int wave = t >> 6, lane = t & 63;
    int wr = (wave >> 1) * 64;
    int wc = (wave & 1) * 64;
    int m0 = blockIdx.y * 128;
    int n0 = blockIdx.x * 128;

    floatx4 acc[4][4];
#pragma unroll
    for (int i = 0; i < 4; i++)
#pragma unroll
        for (int j = 0; j < 4; j++) acc[i][j] = (floatx4){0.f, 0.f, 0.f, 0.f};

    int q0 = t >> 7, r0 = t & 127;
    int q1 = (256 + t) >> 7, r1 = (256 + t) & 127;
    int ga0 = m0 + r0; ga0 = ga0 < M ? ga0 : M - 1;
    int ga1 = m0 + r1; ga1 = ga1 < M ? ga1 : M - 1;
    const f16* pa0 = A + (size_t)ga0 * K + q0 * 8;
    const f16* pa1 = A + (size_t)ga1 * K + q1 * 8;
    const f16* pb0 = Bt + (size_t)(n0 + r0) * K + q0 * 8;
    const f16* pb1 = Bt + (size_t)(n0 + r1) * K + q1 * 8;
    f16* la0 = As + (size_t)t * 8;
    f16* la1 = As + (size_t)(256 + t) * 8;
    f16* lb0 = Bs + (size_t)t * 8;
    f16* lb1 = Bs + (size_t)(256 + t) * 8;

    int fq = lane >> 4, fr = lane & 15;
    int aoff[4], boff[4];
#pragma unroll
    for (int i = 0; i < 4; i++) {
        aoff[i] = (fq * 128 + wr + i * 16 + fr) * 8;
        boff[i] = (fq * 128 + wc + i * 16 + fr) * 8;
    }

    for (int k0 = 0; k0 < K; k0 += 32) {
        __syncthreads();
        load_lds16(pa0 + k0, la0);
        load_lds16(pa1 + k0, la1);
        load_lds16(pb0 + k0, lb0);
        load_lds16(pb1 + k0, lb1);
        __syncthreads();
        half8 af[4], bf[4];
#pragma unroll
        for (int i = 0; i < 4; i++) af[i] = *(const half8*)&As[aoff[i]];
#pragma unroll
        for (int j = 0; j < 4; j++) bf[j] = *(const half8*)&Bs[boff[j]];
#pragma unroll
        for (int i = 0; i < 4; i++)
#pragma unroll
            for (int j = 0; j < 4; j++)
                acc[i][j] = __builtin_amdgcn_mfma_f32_16x16x32_f16(af[i], bf[j], acc[i][j],
                                                                   0, 0, 0);
    }

    // C/D layout: col = lane&15, row = (lane>>4)*4 + reg
    int cr = lane >> 4, cc = lane & 15;
#pragma unroll
    for (int i = 0; i < 4; i++) {
#pragma unroll
        for (int r = 0; r < 4; r++) {
            int row = m0 + wr + i * 16 + cr * 4 + r;
            if (row < M) {
#pragma unroll
                for (int j = 0; j < 4; j++)
                    C16[(size_t)row * N + n0 + wc + j * 16 + cc] = (f16)acc[i][j][r];
            }
        }
    }
}

// ---------------- fused attention + aggregation ----------------
// Per node n (block of 256): walk CSR row, compute p inline (single-pass softmax,
// denominators are local sums), aggregate fp16 messages, BN/ReLU, and for concat
// layers also compute next-layer asrc/adst from the fp32 activations in registers.
__global__ void agg_kernel(const f16* __restrict__ h16, const float* __restrict__ asrc,
                           const float* __restrict__ adst, const float* __restrict__ ae_self,
                           const float* __restrict__ Mmat, const float* __restrict__ ea,
                           const int* __restrict__ ei, const int* __restrict__ indptr,
                           const int* __restrict__ sorted, const float* __restrict__ bias012,
                           const float* __restrict__ bias3, const float* __restrict__ bn_g,
                           const float* __restrict__ bn_b, const float* __restrict__ bn_m,
                           const float* __restrict__ bn_v, const float* __restrict__ wsv,
                           const float* __restrict__ wdv, f16* __restrict__ out16,
                           float* __restrict__ asrc_n, float* __restrict__ adst_n,
                           float* __restrict__ out3, int layer, int concat) {
    __shared__ float buf[1024];
    __shared__ float red[32];
    int n = blockIdx.x, t = threadIdx.x;
    int h = t >> 6, lane = t & 63;
    int c4 = t * 4;
    float Ml0 = Mmat[layer * 12 + h];
    float Ml1 = Mmat[layer * 12 + 4 + h];
    float Ml2 = Mmat[layer * 12 + 8 + h];
    float adst_nh = adst[n * 4 + h];

    // self-loop
    float r_self = asrc[n * 4 + h] + adst_nh + ae_self[layer * 4 + h];
    r_self = (r_self > 0.f) ? r_self : 0.2f * r_self;
    float p = __expf(r_self);
    float denom = p;
    float ax, ay, az, aw;
    {
        f16x4 v = *(const f16x4*)&h16[(size_t)n * HC + c4];
        ax = p * (float)v[0]; ay = p * (float)v[1];
        az = p * (float)v[2]; aw = p * (float)v[3];
    }
    int s = indptr[n], epos = indptr[n + 1];
    for (int idx = s; idx < epos; idx++) {
        int eid = sorted[idx];
        int sr = ei[eid];
        float a0 = ea[eid * 3 + 0], a1 = ea[eid * 3 + 1], a2 = ea[eid * 3 + 2];
        float r = asrc[sr * 4 + h] + adst_nh + a0 * Ml0 + a1 * Ml1 + a2 * Ml2;
        r = (r > 0.f) ? r : 0.2f * r;
        float pe = __expf(r);
        denom += pe;
        f16x4 v = *(const f16x4*)&h16[(size_t)sr * HC + c4];
        ax += pe * (float)v[0];
        ay += pe * (float)v[1];
        az += pe * (float)v[2];
        aw += pe * (float)v[3];
    }
    float inv = 1.0f / (denom + 1e-16f);
    ax *= inv; ay *= inv; az *= inv; aw *= inv;

    if (concat) {
        float vals[4] = {ax, ay, az, aw};
        f16x4 o;
        float sp[4] = {0.f, 0.f, 0.f, 0.f}, dp[4] = {0.f, 0.f, 0.f, 0.f};
#pragma unroll
        for (int k = 0; k < 4; k++) {
            int j = c4 + k;
            float val = vals[k] + bias012[layer * HC + j];
            float g = bn_g[layer * HC + j];
            float be = bn_b[layer * HC + j];
            float mu = bn_m[layer * HC + j];
            float va = bn_v[layer * HC + j];
            val = (val - mu) * (g * rsqrtf(va + 1e-5f)) + be;
            val = fmaxf(val, 0.f);
            o[k] = (f16)val;
            float4 ws4 = *(const float4*)&wsv[(size_t)j * 4];
            float4 wd4 = *(const float4*)&wdv[(size_t)j * 4];
            sp[0] += val * ws4.x; sp[1] += val * ws4.y;
            sp[2] += val * ws4.z; sp[3] += val * ws4.w;
            dp[0] += val * wd4.x; dp[1] += val * wd4.y;
            dp[2] += val * wd4.z; dp[3] += val * wd4.w;
        }
        *(f16x4*)&out16[(size_t)n * HC + c4] = o;
        // block-reduce 8 values
#pragma unroll
        for (int m = 1; m < 64; m <<= 1) {
#pragma unroll
            for (int j = 0; j < 4; j++) {
                sp[j] += __shfl_xor(sp[j], m);
                dp[j] += __shfl_xor(dp[j], m);
            }
        }
        if (lane == 0) {
#pragma unroll
            for (int j = 0; j < 4; j++) {
                red[h * 8 + j] = sp[j];
                red[h * 8 + 4 + j] = dp[j];
            }
        }
        __syncthreads();
        if (t < 8) {
            float v = red[t] + red[8 + t] + red[16 + t] + red[24 + t];
            if (t < 4) asrc_n[n * 4 + t] = v;
            else adst_n[n * 4 + (t - 4)] = v;
        }
    } else {
        buf[c4 + 0] = ax;
        buf[c4 + 1] = ay;
        buf[c4 + 2] = az;
        buf[c4 + 3] = aw;
        __syncthreads();
        if (t < 64) {
#pragma unroll
            for (int k = 0; k < 4; k++) {
                int c = t * 4 + k;
                float v2 = 0.25f * (buf[c] + buf[256 + c] + buf[512 + c] + buf[768 + c]) +
                           bias3[c];
                out3[(size_t)n * CC + c] = v2;
            }
        }
    }
}

// ---------------- readout ----------------
__global__ void gate_kernel(const float* __restrict__ h3, const float* __restrict__ gw,
                            const float* __restrict__ gb, float* gate) {
    int node = blockIdx.x * 4 + (threadIdx.x >> 6);
    int lane = threadIdx.x & 63;
    if (node >= NN) return;
    const float4 hv = *(const float4*)&h3[(size_t)node * CC + lane * 4];
    const float4 w4 = *(const float4*)&gw[lane * 4];
    float s = hv.x * w4.x + hv.y * w4.y + hv.z * w4.z + hv.w * w4.w;
    for (int o = 32; o; o >>= 1) s += __shfl_down(s, o);
    if (lane == 0) gate[node] = s + gb[0];
}

__global__ void graphagg_kernel(const float* __restrict__ gate, const float* __restrict__ h3,
                                const int* __restrict__ bptr, float* __restrict__ graph) {
    __shared__ float red[256];
    __shared__ float wn[256];
    int b = blockIdx.x, t = threadIdx.x;
    int s = bptr[b], epos = bptr[b + 1];
    float m = -3.4e38f;
    for (int n = s + t; n < epos; n += 256) m = fmaxf(m, gate[n]);
    red[t] = m;
    __syncthreads();
    for (int o = 128; o; o >>= 1) {
        if (t < o) red[t] = fmaxf(red[t], red[t + o]);
        __syncthreads();
    }
    float mval = red[0];
    __syncthreads();
    float sum = 0.f;
    for (int n = s + t; n < epos; n += 256) sum += __expf(gate[n] - mval);
    red[t] = sum;
    __syncthreads();
    for (int o = 128; o; o >>= 1) {
        if (t < o) red[t] += red[t + o];
        __syncthreads();
    }
    float ssum = red[0];
    __syncthreads();
    float acc = 0.f;
    for (int base = s; base < epos; base += 256) {
        int n = base + t;
        wn[t] = (n < epos) ? __expf(gate[n] - mval) : 0.f;
        __syncthreads();
        int cnt = min(256, epos - base);
        for (int j = 0; j < cnt; j++) acc += wn[j] * h3[(size_t)(base + j) * CC + t];
        __syncthreads();
    }
    graph[b * CC + t] = acc / (ssum + 1e-16f);
}

__global__ void proj_kernel(const float* __restrict__ graph, const float* __restrict__ pw,
                            const float* __restrict__ pb, float* __restrict__ out) {
    __shared__ float g[256];
    int b = blockIdx.x, t = threadIdx.x;
    g[t] = graph[b * CC + t];
    __syncthreads();
    for (int j = t; j < 1024; j += 256) {
        float acc = pb[j];
        for (int c = 0; c < 256; c++) acc += g[c] * pw[c * 1024 + j];
        out[(size_t)b * 1024 + j] = acc;
    }
}

// ---------------- host ----------------
extern "C" void kernel_launch(void* const* d_in, const int* in_sizes, int n_in,
                              void* d_out, int out_size, void* d_ws, size_t ws_size,
                              hipStream_t stream) {
    const float* x = (const float*)d_in[0];
    const int* ei = (const int*)d_in[1];
    const float* ea = (const float*)d_in[2];
    const int* batch = (const int*)d_in[3];
    const float* w0 = (const float*)d_in[4];
    const float* w_rest = (const float*)d_in[5];
    const float* w_edge = (const float*)d_in[6];
    const float* att_src = (const float*)d_in[7];
    const float* att_dst = (const float*)d_in[8];
    const float* att_edge = (const float*)d_in[9];
    const float* bias012 = (const float*)d_in[10];
    const float* bias3 = (const float*)d_in[11];
    const float* bn_g = (const float*)d_in[12];
    const float* bn_b = (const float*)d_in[13];
    const float* bn_m = (const float*)d_in[14];
    const float* bn_v = (const float*)d_in[15];
    const float* gate_w = (const float*)d_in[16];
    const float* gate_b = (const float*)d_in[17];
    const float* proj_w = (const float*)d_in[18];
    const float* proj_b = (const float*)d_in[19];
    float* out = (float*)d_out;

    float* ws = (float*)d_ws;
    size_t off = 0;
    f16* h_lin = (f16*)(ws + off); off += (size_t)NN * HC / 2;   // GEMM output (messages)
    f16* h_in = (f16*)(ws + off); off += (size_t)NN * HC / 2;    // agg output / GEMM input
    float* h3 = ws + off; off += (size_t)NN * CC;                // layer-3 output
    f16* wt = (f16*)(ws + off); off += (size_t)3 * HC * HC / 2;  // W^T fp16
    float* asrcA = ws + off; off += (size_t)NN * 4;              // ping-pong alpha buffers
    float* adstA = ws + off; off += (size_t)NN * 4;
    float* asrcB = ws + off; off += (size_t)NN * 4;
    float* adstB = ws + off; off += (size_t)NN * 4;
    float* wsv = ws + off; off += (size_t)3 * HC * 4;            // W·a_src per layer 1..3
    float* wdv = ws + off; off += (size_t)3 * HC * 4;
    float* w0s = ws + off; off += 28;
    float* w0d = ws + off; off += 28;
    float* gate = ws + off; off += (size_t)NN;
    float* graph = ws + off; off += (size_t)BB * CC;
    float* ea_sums = ws + off; off += 4;
    float* Mmat = ws + off; off += 48;
    float* ae_self = ws + off; off += 16;
    int* counts = (int*)(ws + off); off += NN;
    int* indptr = (int*)(ws + off); off += NN + 1;
    int* fill = (int*)(ws + off); off += NN;
    int* sorted = (int*)(ws + off); off += EE;
    int* bptr = (int*)(ws + off); off += BB + 1;

    hipMemsetAsync(ea_sums, 0, 4 * sizeof(float), stream);
    hipMemsetAsync(counts, 0, NN * sizeof(int), stream);
    hipMemsetAsync(fill, 0, NN * sizeof(int), stream);

    ea_sum_kernel<<<64, 256, 0, stream>>>(ea, ea_sums, EE);
    hist_kernel<<<(EE + 255) / 256, 256, 0, stream>>>(ei, counts, EE);
    scan_kernel<<<1, 1024, 0, stream>>>(counts, indptr, NN);
    scatter_kernel<<<(EE + 255) / 256, 256, 0, stream>>>(ei, indptr, fill, sorted, EE);
    bptr_kernel<<<(NN + 255) / 256, 256, 0, stream>>>(batch, bptr, NN, BB);
    wconv_kernel<<<dim3(16, 16, 3), 256, 0, stream>>>(w_rest, wt);
    mmat_all_kernel<<<4, 256, 0, stream>>>(w_edge, att_edge, ea_sums, Mmat, ae_self,
                                           1.0f / EE);
    wvec_kernel<<<dim3(1024, 3), 256, 0, stream>>>(w_rest, att_src, att_dst, wsv, wdv);
    w0vec_kernel<<<7, 256, 0, stream>>>(w0, att_src, att_dst, w0s, w0d);
    alpha0_kernel<<<(NN + 255) / 256, 256, 0, stream>>>(x, w0s, w0d, asrcA, adstA);

    float* asrc_cur = asrcA;
    float* adst_cur = adstA;
    float* asrc_nxt = asrcB;
    float* adst_nxt = adstB;
    for (int i = 0; i < 4; i++) {
        if (i == 0) {
            gemm7_kernel<<<dim3(NN, 4), 256, 0, stream>>>(x, w0, h_lin);
        } else {
            mfma_gemm_kernel<<<dim3(HC / 128, (NN + 127) / 128), 256, 0, stream>>>(
                h_in, wt + (size_t)(i - 1) * HC * HC, h_lin, NN, HC, HC);
        }
        agg_kernel<<<NN, 256, 0, stream>>>(
            h_lin, asrc_cur, adst_cur, ae_self, Mmat, ea, ei, indptr, sorted, bias012,
            bias3, bn_g, bn_b, bn_m, bn_v, wsv + (size_t)i * HC * 4,
            wdv + (size_t)i * HC * 4, h_in, asrc_nxt, adst_nxt, h3, i, (i < 3) ? 1 : 0);
        float* tmp = asrc_cur; asrc_cur = asrc_nxt; asrc_nxt = tmp;
        tmp = adst_cur; adst_cur = adst_nxt; adst_nxt = tmp;
    }

    gate_kernel<<<(NN + 3) / 4, 256, 0, stream>>>(h3, gate_w, gate_b, gate);
    graphagg_kernel<<<BB, 256, 0, stream>>>(gate, h3, bptr, graph);
    proj_kernel<<<BB, 256, 0, stream>>>(graph, proj_w, proj_b, out);
}